// Round 1
// baseline (167.879 us; speedup 1.0000x reference)
//
#include <hip/hip_runtime.h>

#define BB 8
#define CC 128

// ---------------- fused inLay: combine -> LDS + sample + box mask; also inits head bias.
// Batch-affine block swizzle (b = bc&7) so batch b's output stays in XCD b's L2.
__global__ __launch_bounds__(256) void inlay_sample_kernel(
    const float* __restrict__ x, const float* __restrict__ lin,
    const float* __restrict__ geo, const float* __restrict__ box,
    const float* __restrict__ db, float* __restrict__ out,
    float* __restrict__ head) {
  const int H = 64, W = 64, HW = 4096;
  __shared__ __align__(16) float cp[64 * 68];
  int bc = blockIdx.x;
  int b = bc & 7;          // batch -> XCD
  int c = bc >> 3;
  int tid = threadIdx.x;
  if (bc == 0 && tid < 80) head[tid] = db[tid % 10];  // bias init for atomic dense
  const float* xb = x + (size_t)b * 3 * HW;

  float w0 = lin[c * 3 + 0], w1 = lin[c * 3 + 1], w2 = lin[c * 3 + 2];

#pragma unroll
  for (int k = 0; k < 4; ++k) {
    int i4 = tid + k * 256;
    int base = i4 * 4;
    float4 f0 = *reinterpret_cast<const float4*>(&xb[base]);
    float4 f1 = *reinterpret_cast<const float4*>(&xb[HW + base]);
    float4 f2 = *reinterpret_cast<const float4*>(&xb[2 * HW + base]);
    float4 cv;
    cv.x = w0 * f0.x + w1 * f1.x + w2 * f2.x;
    cv.y = w0 * f0.y + w1 * f1.y + w2 * f2.y;
    cv.z = w0 * f0.z + w1 * f1.z + w2 * f2.z;
    cv.w = w0 * f0.w + w1 * f1.w + w2 * f2.w;
    int h = i4 >> 4, w = (i4 & 15) * 4;
    *reinterpret_cast<float4*>(&cp[h * 68 + w]) = cv;
  }
  __syncthreads();

  const float* g = geo + c * 6;
  const float* bx = box + c * 6;
  float g0 = g[0], g1 = g[1], g2 = g[2], g3 = g[3], g4 = g[4], g5 = g[5];
  float b0 = bx[0], b1 = bx[1], b2 = bx[2], b3 = bx[3], b4 = bx[4], b5 = bx[5];
  float* o = out + ((size_t)b * CC + c) * HW;

#pragma unroll
  for (int k = 0; k < 16; ++k) {
    int px = tid + k * 256;
    int h = px >> 6, w = px & 63;
    float xs = (2.0f * w + 1.0f) / W - 1.0f;
    float ys = (2.0f * h + 1.0f) / H - 1.0f;
    float gx = g0 * xs + g1 * ys + g2;
    float gy = g3 * xs + g4 * ys + g5;
    float ix = ((gx + 1.0f) * W - 1.0f) * 0.5f;
    float iy = ((gy + 1.0f) * H - 1.0f) * 0.5f;
    float x0 = floorf(ix), y0 = floorf(iy);
    float wx = ix - x0, wy = iy - y0;
    float v[2][2];
#pragma unroll
    for (int dy = 0; dy < 2; ++dy)
#pragma unroll
      for (int dx = 0; dx < 2; ++dx) {
        float xf = x0 + dx, yf = y0 + dy;
        bool valid = (xf >= 0.0f) && (xf <= 63.0f) && (yf >= 0.0f) && (yf <= 63.0f);
        int xi = (int)fminf(fmaxf(xf, 0.0f), 63.0f);
        int yi = (int)fminf(fmaxf(yf, 0.0f), 63.0f);
        v[dy][dx] = valid ? cp[yi * 68 + xi] : 0.0f;
      }
    float samp = (1.0f - wy) * ((1.0f - wx) * v[0][0] + wx * v[0][1]) +
                 wy * ((1.0f - wx) * v[1][0] + wx * v[1][1]);

    float bgx = b0 * xs + b1 * ys + b2;
    float bgy = b3 * xs + b4 * ys + b5;
    float bix = ((bgx + 1.0f) * W - 1.0f) * 0.5f;
    float biy = ((bgy + 1.0f) * H - 1.0f) * 0.5f;
    float bx0 = floorf(bix), by0 = floorf(biy);
    float bwx = bix - bx0, bwy = biy - by0;
    float m[2][2];
#pragma unroll
    for (int dy = 0; dy < 2; ++dy)
#pragma unroll
      for (int dx = 0; dx < 2; ++dx) {
        float xf = bx0 + dx, yf = by0 + dy;
        m[dy][dx] = ((xf >= 0.0f) && (xf <= 63.0f) && (yf >= 0.0f) && (yf <= 63.0f)) ? 1.0f : 0.0f;
      }
    float mask = (1.0f - bwy) * ((1.0f - bwx) * m[0][0] + bwx * m[0][1]) +
                 bwy * ((1.0f - bwx) * m[1][0] + bwx * m[1][1]);
    o[px] = samp * mask;
  }
}

// ---------------- layer-0 GEMM: 64x64 tile, 4x4/thread, register prefetch ----------
// 1D grid with batch-affine swizzle (b = bx&7) so B-panel reads + C writes stay on XCD b.
__global__ __launch_bounds__(256) void gemm64_kernel(
    const float* __restrict__ lin, const float* __restrict__ x,
    float* __restrict__ y, int HW) {
  const int Ci = 128;
  __shared__ __align__(16) float As[16][68];
  __shared__ __align__(16) float Bs[16][64];
  int bx = blockIdx.x;
  int b = bx & 7;
  int t = bx >> 3;               // 0..127: 2 row tiles x 64 col tiles
  int row0 = (t & 1) * 64;
  int col0 = (t >> 1) * 64;
  const float* xb = x + (size_t)b * Ci * HW;
  float* yb = y + (size_t)b * CC * HW;
  int tid = threadIdx.x;
  int tx = tid & 15, ty = tid >> 4;
  int m = tid >> 2, kq = (tid & 3) * 4;
  int kk = tid >> 4, n4 = (tid & 15) * 4;
  float acc[4][4] = {};
  float4 ra = *reinterpret_cast<const float4*>(&lin[(row0 + m) * Ci + kq]);
  float4 rb = *reinterpret_cast<const float4*>(&xb[(size_t)kk * HW + col0 + n4]);
  for (int k0 = 0; k0 < 128; k0 += 16) {
    __syncthreads();
    As[kq + 0][m] = ra.x; As[kq + 1][m] = ra.y; As[kq + 2][m] = ra.z; As[kq + 3][m] = ra.w;
    *reinterpret_cast<float4*>(&Bs[kk][n4]) = rb;
    __syncthreads();
    if (k0 + 16 < 128) {
      ra = *reinterpret_cast<const float4*>(&lin[(row0 + m) * Ci + k0 + 16 + kq]);
      rb = *reinterpret_cast<const float4*>(&xb[(size_t)(k0 + 16 + kk) * HW + col0 + n4]);
    }
#pragma unroll
    for (int kki = 0; kki < 16; ++kki) {
      float4 a4 = *reinterpret_cast<const float4*>(&As[kki][ty * 4]);
      float4 b4 = *reinterpret_cast<const float4*>(&Bs[kki][tx * 4]);
      float a[4] = {a4.x, a4.y, a4.z, a4.w};
      float bv[4] = {b4.x, b4.y, b4.z, b4.w};
#pragma unroll
      for (int i = 0; i < 4; i++)
#pragma unroll
        for (int j = 0; j < 4; j++) acc[i][j] += a[i] * bv[j];
    }
  }
#pragma unroll
  for (int i = 0; i < 4; i++) {
    float* yr = yb + (size_t)(row0 + ty * 4 + i) * HW + col0 + tx * 4;
    *reinterpret_cast<float4*>(yr) = make_float4(acc[i][0], acc[i][1], acc[i][2], acc[i][3]);
  }
}

// ---------------- fused sample(64x64) + MaxPool2d_G -> 32x32, 1024 threads ---------
// Changes: batch-affine swizzle; sliding-window box sums in phases 2 and 3.
__global__ __launch_bounds__(1024, 4) void sampmax_kernel(
    const float* __restrict__ y, const float* __restrict__ geo,
    const float* __restrict__ box, float* __restrict__ out) {
  __shared__ __align__(16) float sp[64 * 68];      // sampled plane, padded stride
  __shared__ __align__(16) float arena[64 * 100];  // pl (ph1) then cb (ph2-3)
  __shared__ float wv[16];
  __shared__ int wi[16];
  __shared__ int am_s;
  float* pl = arena;
  float* cb = arena;

  int bc = blockIdx.x;
  int b = bc & 7;          // batch -> XCD (matches producer gemm64 and consumer fused32)
  int c = bc >> 3;
  int tid = threadIdx.x;

  const float* plane = y + ((size_t)b * CC + c) * 4096;
  *reinterpret_cast<float4*>(&pl[tid * 4]) = *reinterpret_cast<const float4*>(&plane[tid * 4]);
  __syncthreads();

  {
    const float* g = geo + c * 6;
    const float* bx = box + c * 6;
    float g0 = g[0], g1 = g[1], g2 = g[2], g3 = g[3], g4 = g[4], g5 = g[5];
    float b0 = bx[0], b1 = bx[1], b2 = bx[2], b3 = bx[3], b4 = bx[4], b5 = bx[5];
#pragma unroll
    for (int k = 0; k < 4; ++k) {
      int px = tid + k * 1024;
      int h = px >> 6, w = px & 63;
      float xs = (2.0f * w + 1.0f) / 64.0f - 1.0f;
      float ys = (2.0f * h + 1.0f) / 64.0f - 1.0f;
      float gx = g0 * xs + g1 * ys + g2;
      float gy = g3 * xs + g4 * ys + g5;
      float ix = ((gx + 1.0f) * 64.0f - 1.0f) * 0.5f;
      float iy = ((gy + 1.0f) * 64.0f - 1.0f) * 0.5f;
      float x0 = floorf(ix), y0 = floorf(iy);
      float wx = ix - x0, wy = iy - y0;
      float v[2][2];
#pragma unroll
      for (int dy = 0; dy < 2; ++dy)
#pragma unroll
        for (int dx = 0; dx < 2; ++dx) {
          float xf = x0 + dx, yf = y0 + dy;
          bool valid = (xf >= 0.0f) && (xf <= 63.0f) && (yf >= 0.0f) && (yf <= 63.0f);
          int xi = (int)fminf(fmaxf(xf, 0.0f), 63.0f);
          int yi = (int)fminf(fmaxf(yf, 0.0f), 63.0f);
          v[dy][dx] = valid ? pl[yi * 64 + xi] : 0.0f;
        }
      float samp = (1.0f - wy) * ((1.0f - wx) * v[0][0] + wx * v[0][1]) +
                   wy * ((1.0f - wx) * v[1][0] + wx * v[1][1]);
      float bgx = b0 * xs + b1 * ys + b2;
      float bgy = b3 * xs + b4 * ys + b5;
      float bix = ((bgx + 1.0f) * 64.0f - 1.0f) * 0.5f;
      float biy = ((bgy + 1.0f) * 64.0f - 1.0f) * 0.5f;
      float bx0 = floorf(bix), by0 = floorf(biy);
      float bwx = bix - bx0, bwy = biy - by0;
      float m[2][2];
#pragma unroll
      for (int dy = 0; dy < 2; ++dy)
#pragma unroll
        for (int dx = 0; dx < 2; ++dx) {
          float xf = bx0 + dx, yf = by0 + dy;
          m[dy][dx] = ((xf >= 0.0f) && (xf <= 63.0f) && (yf >= 0.0f) && (yf <= 63.0f)) ? 1.0f : 0.0f;
        }
      float mask = (1.0f - bwy) * ((1.0f - bwx) * m[0][0] + bwx * m[0][1]) +
                   bwy * ((1.0f - bwx) * m[1][0] + bwx * m[1][1]);
      sp[h * 68 + w] = samp * mask;
    }
  }
  __syncthreads();

  // Phase 2: vertical 32-row box sums, sliding window across the 4 rows per strip.
  if (tid < 256) {
    int strip = tid >> 4, w4 = (tid & 15) * 4;
    int h0 = strip * 4;
    float4 a = make_float4(0.f, 0.f, 0.f, 0.f);
    float4 keep0 = a, keep1 = a, keep2 = a;
#pragma unroll
    for (int j = 0; j < 32; ++j) {
      int r = h0 + j - 16;
      bool valid = (r >= 0) && (r < 64);
      int rc = valid ? r : 0;
      float4 f = *reinterpret_cast<const float4*>(&sp[rc * 68 + w4]);
      f.x = valid ? f.x : 0.0f; f.y = valid ? f.y : 0.0f;
      f.z = valid ? f.z : 0.0f; f.w = valid ? f.w : 0.0f;
      if (j == 0) keep0 = f;
      if (j == 1) keep1 = f;
      if (j == 2) keep2 = f;
      a.x += f.x; a.y += f.y; a.z += f.z; a.w += f.w;
    }
    *reinterpret_cast<float4*>(&cb[(h0 + 0) * 100 + 16 + w4]) = a;
#pragma unroll
    for (int j = 32; j < 35; ++j) {
      int r = h0 + j - 16;
      bool valid = (r < 64);
      int rc = valid ? r : 0;
      float4 f = *reinterpret_cast<const float4*>(&sp[rc * 68 + w4]);
      f.x = valid ? f.x : 0.0f; f.y = valid ? f.y : 0.0f;
      f.z = valid ? f.z : 0.0f; f.w = valid ? f.w : 0.0f;
      float4 kp = (j == 32) ? keep0 : ((j == 33) ? keep1 : keep2);
      a.x += f.x - kp.x; a.y += f.y - kp.y; a.z += f.z - kp.z; a.w += f.w - kp.w;
      *reinterpret_cast<float4*>(&cb[(h0 + j - 31) * 100 + 16 + w4]) = a;
    }
  } else if (tid < 768) {
    int l = tid - 256;
    int row = l >> 3, gq = l & 7;
    int base = row * 100 + ((gq < 4) ? gq * 4 : 80 + (gq - 4) * 4);
    *reinterpret_cast<float4*>(&cb[base]) = make_float4(0.f, 0.f, 0.f, 0.f);
  }
  __syncthreads();

  // Phase 3: horizontal 32-col box sums, sliding window across 4 cols per thread.
  float best = -3.402823466e+38f;
  int bidx = 0x7fffffff;
  {
    int h = tid >> 4, w4 = (tid & 15) * 4;
    float s0 = 0.f, k0 = 0.f, k1 = 0.f, k2 = 0.f;
#pragma unroll
    for (int q = 0; q < 8; ++q) {
      float4 f = *reinterpret_cast<const float4*>(&cb[h * 100 + w4 + 4 * q]);
      if (q == 0) { k0 = f.x; k1 = f.y; k2 = f.z; }
      s0 += f.x; s0 += f.y; s0 += f.z; s0 += f.w;
    }
    float4 ft = *reinterpret_cast<const float4*>(&cb[h * 100 + w4 + 32]);
    float s1 = s0 - k0 + ft.x;
    float s2 = s1 - k1 + ft.y;
    float s3 = s2 - k2 + ft.z;
    float sv[4] = {s0, s1, s2, s3};
#pragma unroll
    for (int d = 0; d < 4; ++d) {
      int i = (h << 6) + w4 + d;
      if (sv[d] > best) { best = sv[d]; bidx = i; }
    }
  }
#pragma unroll
  for (int off = 32; off > 0; off >>= 1) {
    float v2 = __shfl_down(best, off);
    int i2 = __shfl_down(bidx, off);
    if (v2 > best || (v2 == best && i2 < bidx)) { best = v2; bidx = i2; }
  }
  if ((tid & 63) == 0) { wv[tid >> 6] = best; wi[tid >> 6] = bidx; }
  __syncthreads();
  if (tid == 0) {
    float bv = wv[0]; int bi = wi[0];
#pragma unroll
    for (int k = 1; k < 16; ++k)
      if (wv[k] > bv || (wv[k] == bv && wi[k] < bi)) { bv = wv[k]; bi = wi[k]; }
    am_s = bi;
  }
  __syncthreads();

  int am = am_s;
  int r = am >> 6, cx = am & 63;
  float* o = out + ((size_t)b * CC + c) * 1024;
  {
    int oi = tid >> 5, oj = tid & 31;
    int rr = r + oi - 16, cj = cx + oj - 16;
    bool v = (rr >= 0) && (rr < 64) && (cj >= 0) && (cj < 64);
    int rrc = v ? rr : 0, cjc = v ? cj : 0;
    o[tid] = v ? sp[rrc * 68 + cjc] : 0.0f;
  }
}

// ---------------- fused 32x32 layer: GEMM (4 ch/block, grid 256, 512 thr) + sample --
// 4 ch/block halves per-layer L2 GEMM traffic (268MB -> 134MB). POOL path also folds
// the dense head in via per-block atomicAdd (bias pre-written by inlay).
template <bool POOL>
__global__ __launch_bounds__(512) void fused32_kernel(
    const float* __restrict__ lin, const float* __restrict__ x,
    const float* __restrict__ geo, const float* __restrict__ box,
    float* __restrict__ out, const float* __restrict__ dw,
    float* __restrict__ head) {
  const int H = 32, W = 32, HW = 1024;
  __shared__ __align__(16) float pls[4][1024];
  __shared__ float wred[32];
  __shared__ float wsum[4];
  int b = blockIdx.x & 7;                 // XCD swizzle: batch per XCD
  int c0 = (blockIdx.x >> 3) * 4;
  int tid = threadIdx.x;
  const float* xb = x + (size_t)b * 128 * HW;
  const float* l0 = lin + (c0 + 0) * 128;
  const float* l1 = lin + (c0 + 1) * 128;
  const float* l2 = lin + (c0 + 2) * 128;
  const float* l3 = lin + (c0 + 3) * 128;
  int px2 = tid * 2;

  float2 a0 = make_float2(0.f, 0.f), a1 = a0, a2 = a0, a3 = a0;
#pragma unroll 8
  for (int k = 0; k < 128; ++k) {
    float2 xv = *reinterpret_cast<const float2*>(&xb[(size_t)k * HW + px2]);
    float s0 = l0[k], s1 = l1[k], s2 = l2[k], s3 = l3[k];  // block-uniform -> s_load
    a0.x += s0 * xv.x; a0.y += s0 * xv.y;
    a1.x += s1 * xv.x; a1.y += s1 * xv.y;
    a2.x += s2 * xv.x; a2.y += s2 * xv.y;
    a3.x += s3 * xv.x; a3.y += s3 * xv.y;
  }
  *reinterpret_cast<float2*>(&pls[0][px2]) = a0;
  *reinterpret_cast<float2*>(&pls[1][px2]) = a1;
  *reinterpret_cast<float2*>(&pls[2][px2]) = a2;
  *reinterpret_cast<float2*>(&pls[3][px2]) = a3;
  __syncthreads();

  float psum[4] = {0.f, 0.f, 0.f, 0.f};
#pragma unroll
  for (int c = 0; c < 4; ++c) {
    const float* g = geo + (c0 + c) * 6;
    const float* bxp = box + (c0 + c) * 6;
    float g0 = g[0], g1 = g[1], g2 = g[2], g3 = g[3], g4 = g[4], g5 = g[5];
    float b0 = bxp[0], b1 = bxp[1], b2 = bxp[2], b3 = bxp[3], b4 = bxp[4], b5 = bxp[5];
    float* o = out + ((size_t)b * CC + c0 + c) * HW;
    const float* pl = pls[c];
#pragma unroll
    for (int k = 0; k < 2; ++k) {
      int px = tid + k * 512;
      int h = px >> 5, w = px & 31;
      float xs = (2.0f * w + 1.0f) / W - 1.0f;
      float ys = (2.0f * h + 1.0f) / H - 1.0f;
      float gx = g0 * xs + g1 * ys + g2;
      float gy = g3 * xs + g4 * ys + g5;
      float ix = ((gx + 1.0f) * W - 1.0f) * 0.5f;
      float iy = ((gy + 1.0f) * H - 1.0f) * 0.5f;
      float x0 = floorf(ix), y0 = floorf(iy);
      float wx = ix - x0, wy = iy - y0;
      float v[2][2];
#pragma unroll
      for (int dy = 0; dy < 2; ++dy)
#pragma unroll
        for (int dx = 0; dx < 2; ++dx) {
          float xf = x0 + dx, yf = y0 + dy;
          bool valid = (xf >= 0.0f) && (xf <= 31.0f) && (yf >= 0.0f) && (yf <= 31.0f);
          int xi = (int)fminf(fmaxf(xf, 0.0f), 31.0f);
          int yi = (int)fminf(fmaxf(yf, 0.0f), 31.0f);
          v[dy][dx] = valid ? pl[yi * 32 + xi] : 0.0f;
        }
      float samp = (1.0f - wy) * ((1.0f - wx) * v[0][0] + wx * v[0][1]) +
                   wy * ((1.0f - wx) * v[1][0] + wx * v[1][1]);
      float bgx = b0 * xs + b1 * ys + b2;
      float bgy = b3 * xs + b4 * ys + b5;
      float bix = ((bgx + 1.0f) * W - 1.0f) * 0.5f;
      float biy = ((bgy + 1.0f) * H - 1.0f) * 0.5f;
      float bx0 = floorf(bix), by0 = floorf(biy);
      float bwx = bix - bx0, bwy = biy - by0;
      float m[2][2];
#pragma unroll
      for (int dy = 0; dy < 2; ++dy)
#pragma unroll
        for (int dx = 0; dx < 2; ++dx) {
          float xf = bx0 + dx, yf = by0 + dy;
          m[dy][dx] = ((xf >= 0.0f) && (xf <= 31.0f) && (yf >= 0.0f) && (yf <= 31.0f)) ? 1.0f : 0.0f;
        }
      float mask = (1.0f - bwy) * ((1.0f - bwx) * m[0][0] + bwx * m[0][1]) +
                   bwy * ((1.0f - bwx) * m[1][0] + bwx * m[1][1]);
      float res = samp * mask;
      o[px] = res;
      if (POOL) psum[c] += res;
    }
  }
  if (POOL) {
    int lane = tid & 63, wid = tid >> 6;  // 8 waves
#pragma unroll
    for (int c = 0; c < 4; ++c) {
      float r = psum[c];
#pragma unroll
      for (int off = 32; off > 0; off >>= 1) r += __shfl_down(r, off);
      if (lane == 0) wred[c * 8 + wid] = r;
    }
    __syncthreads();
    if (tid < 4) {
      float t = 0.f;
#pragma unroll
      for (int w = 0; w < 8; ++w) t += wred[tid * 8 + w];
      wsum[tid] = t * (1.0f / 1024.0f);
    }
    __syncthreads();
    if (tid < 10) {
      float s = 0.f;
#pragma unroll
      for (int c = 0; c < 4; ++c) s += wsum[c] * dw[tid * 128 + c0 + c];
      atomicAdd(&head[b * 10 + tid], s);
    }
  }
}

extern "C" void kernel_launch(void* const* d_in, const int* in_sizes, int n_in,
                              void* d_out, int out_size, void* d_ws, size_t ws_size,
                              hipStream_t stream) {
  const float* x     = (const float*)d_in[0];   // [8,3,64,64]
  const float* geo0  = (const float*)d_in[1];   // [128,2,3]
  const float* lin0  = (const float*)d_in[2];   // [128,3]
  const float* box0  = (const float*)d_in[3];   // [128,2,3]
  const float* geos  = (const float*)d_in[4];   // [3,128,2,3]
  const float* lins  = (const float*)d_in[5];   // [3,128,128]
  const float* boxes = (const float*)d_in[6];   // [3,128,2,3]
  const float* dw    = (const float*)d_in[7];   // [10,128]
  const float* db    = (const float*)d_in[8];   // [10]

  float* out  = (float*)d_out;      // [8,10] then feat [8,128,32,32]
  float* feat = out + 80;
  float* ws   = (float*)d_ws;
  float* ws0  = ws;                 // 16 MB
  float* ws1  = ws + 4194304;       // 16 MB

  // inLay: fused combine(Ci=3) + sample -> ws1; also writes head bias
  inlay_sample_kernel<<<dim3(BB * CC), 256, 0, stream>>>(x, lin0, geo0, box0, db, ws1, out);
  // layer 0: combine (64x64 tiles, batch-affine) -> fused sample+maxpool -> 32x32
  gemm64_kernel<<<dim3(1024), 256, 0, stream>>>(lins, ws1, ws0, 4096);
  sampmax_kernel<<<dim3(BB * CC), 1024, 0, stream>>>(ws0, geos, boxes, ws1);
  // layer 2: fused GEMM + sample (4 ch/block, grid 256)
  fused32_kernel<false><<<dim3(256), 512, 0, stream>>>(lins + 16384, ws1, geos + 768, boxes + 768, ws0, nullptr, nullptr);
  // layer 3: fused GEMM + sample + mean-pool + atomic dense head, feat straight to d_out
  fused32_kernel<true><<<dim3(256), 512, 0, stream>>>(lins + 32768, ws0, geos + 1536, boxes + 1536, feat, dw, out);
}

// Round 2
// 157.466 us; speedup vs baseline: 1.0661x; 1.0661x over previous
//
#include <hip/hip_runtime.h>

#define BB 8
#define CC 128

// Bilinear sample from a zero-border padded LDS plane.
// pl is [H+3][stride] with interior pixel (r,c) at pl[(r+1)*stride + (c+1)],
// border rows/cols are 0. Coords clamped to [-1, W]; out-of-range taps read 0.
// Bit-exact vs per-tap validity+clamp form.
__device__ __forceinline__ float sample_pad(const float* __restrict__ pl, int stride,
                                            float WF, float ix, float iy) {
  ix = fminf(fmaxf(ix, -1.0f), WF);
  iy = fminf(fmaxf(iy, -1.0f), WF);
  float x0f = floorf(ix), y0f = floorf(iy);
  float wx = ix - x0f, wy = iy - y0f;
  int xi = (int)x0f + 1, yi = (int)y0f + 1;
  const float* p0 = pl + yi * stride + xi;
  float v00 = p0[0], v01 = p0[1], v10 = p0[stride], v11 = p0[stride + 1];
  return (1.0f - wy) * ((1.0f - wx) * v00 + wx * v01) +
         wy * ((1.0f - wx) * v10 + wx * v11);
}

// Factorized box mask: validity of tap(i,j) = X_i * Y_j, so bilinear sum = mx*my.
// Bit-exact vs the 4-tap bilinear of 0/1 values.
__device__ __forceinline__ float box_mask(float bix, float biy, float WM1) {
  float bx0 = floorf(bix), by0 = floorf(biy);
  float bwx = bix - bx0, bwy = biy - by0;
  float mx = (((bx0 >= 0.0f) && (bx0 <= WM1)) ? (1.0f - bwx) : 0.0f) +
             (((bx0 >= -1.0f) && (bx0 <= WM1 - 1.0f)) ? bwx : 0.0f);
  float my = (((by0 >= 0.0f) && (by0 <= WM1)) ? (1.0f - bwy) : 0.0f) +
             (((by0 >= -1.0f) && (by0 <= WM1 - 1.0f)) ? bwy : 0.0f);
  return mx * my;
}

// ---------------- fused inLay: combine -> padded LDS + sample + box mask ----------
__global__ __launch_bounds__(256) void inlay_sample_kernel(
    const float* __restrict__ x, const float* __restrict__ lin,
    const float* __restrict__ geo, const float* __restrict__ box,
    const float* __restrict__ db, float* __restrict__ out,
    float* __restrict__ head) {
  const int H = 64, W = 64, HW = 4096;
  __shared__ float cp[67 * 68];   // padded: rows 0..66, interior rows 1..64 cols 1..64
  int bc = blockIdx.x;
  int c = bc & (CC - 1);
  int b = bc >> 7;
  int tid = threadIdx.x;
  if (bc == 0 && tid < 80) head[tid] = db[tid % 10];  // bias init for atomic dense
  const float* xb = x + (size_t)b * 3 * HW;

  float w0 = lin[c * 3 + 0], w1 = lin[c * 3 + 1], w2 = lin[c * 3 + 2];

  // zero borders: rows 0,65,66 and cols 0,65,66
  if (tid < 68) {
    cp[tid] = 0.0f; cp[65 * 68 + tid] = 0.0f; cp[66 * 68 + tid] = 0.0f;
  } else if (tid < 132) {
    int r = tid - 67;  // 1..64
    cp[r * 68 + 0] = 0.0f; cp[r * 68 + 65] = 0.0f; cp[r * 68 + 66] = 0.0f;
  }

#pragma unroll
  for (int k = 0; k < 4; ++k) {
    int i4 = tid + k * 256;
    int base = i4 * 4;
    float4 f0 = *reinterpret_cast<const float4*>(&xb[base]);
    float4 f1 = *reinterpret_cast<const float4*>(&xb[HW + base]);
    float4 f2 = *reinterpret_cast<const float4*>(&xb[2 * HW + base]);
    int h = i4 >> 4, w = (i4 & 15) * 4;
    float* d = &cp[(h + 1) * 68 + w + 1];
    d[0] = w0 * f0.x + w1 * f1.x + w2 * f2.x;
    d[1] = w0 * f0.y + w1 * f1.y + w2 * f2.y;
    d[2] = w0 * f0.z + w1 * f1.z + w2 * f2.z;
    d[3] = w0 * f0.w + w1 * f1.w + w2 * f2.w;
  }
  __syncthreads();

  const float* g = geo + c * 6;
  const float* bx = box + c * 6;
  float g0 = g[0], g1 = g[1], g2 = g[2], g3 = g[3], g4 = g[4], g5 = g[5];
  float b0 = bx[0], b1 = bx[1], b2 = bx[2], b3 = bx[3], b4 = bx[4], b5 = bx[5];
  float* o = out + ((size_t)b * CC + c) * HW;

#pragma unroll
  for (int k = 0; k < 16; ++k) {
    int px = tid + k * 256;
    int h = px >> 6, w = px & 63;
    float xs = (2.0f * w + 1.0f) / W - 1.0f;
    float ys = (2.0f * h + 1.0f) / H - 1.0f;
    float ix = ((g0 * xs + g1 * ys + g2 + 1.0f) * W - 1.0f) * 0.5f;
    float iy = ((g3 * xs + g4 * ys + g5 + 1.0f) * H - 1.0f) * 0.5f;
    float samp = sample_pad(cp, 68, 64.0f, ix, iy);
    float bix = ((b0 * xs + b1 * ys + b2 + 1.0f) * W - 1.0f) * 0.5f;
    float biy = ((b3 * xs + b4 * ys + b5 + 1.0f) * H - 1.0f) * 0.5f;
    o[px] = samp * box_mask(bix, biy, 63.0f);
  }
}

// ---------------- layer-0 GEMM: 64x64 tile, 4x4/thread, register prefetch ----------
__global__ __launch_bounds__(256) void gemm64_kernel(
    const float* __restrict__ lin, const float* __restrict__ x,
    float* __restrict__ y, int HW) {
  const int Ci = 128;
  __shared__ __align__(16) float As[16][68];
  __shared__ __align__(16) float Bs[16][64];
  int b = blockIdx.z;
  const float* xb = x + (size_t)b * Ci * HW;
  float* yb = y + (size_t)b * CC * HW;
  int tid = threadIdx.x;
  int tx = tid & 15, ty = tid >> 4;
  int row0 = blockIdx.y * 64;
  int col0 = blockIdx.x * 64;
  int m = tid >> 2, kq = (tid & 3) * 4;
  int kk = tid >> 4, n4 = (tid & 15) * 4;
  float acc[4][4] = {};
  float4 ra = *reinterpret_cast<const float4*>(&lin[(row0 + m) * Ci + kq]);
  float4 rb = *reinterpret_cast<const float4*>(&xb[(size_t)kk * HW + col0 + n4]);
  for (int k0 = 0; k0 < 128; k0 += 16) {
    __syncthreads();
    As[kq + 0][m] = ra.x; As[kq + 1][m] = ra.y; As[kq + 2][m] = ra.z; As[kq + 3][m] = ra.w;
    *reinterpret_cast<float4*>(&Bs[kk][n4]) = rb;
    __syncthreads();
    if (k0 + 16 < 128) {
      ra = *reinterpret_cast<const float4*>(&lin[(row0 + m) * Ci + k0 + 16 + kq]);
      rb = *reinterpret_cast<const float4*>(&xb[(size_t)(k0 + 16 + kk) * HW + col0 + n4]);
    }
#pragma unroll
    for (int kki = 0; kki < 16; ++kki) {
      float4 a4 = *reinterpret_cast<const float4*>(&As[kki][ty * 4]);
      float4 b4 = *reinterpret_cast<const float4*>(&Bs[kki][tx * 4]);
      float a[4] = {a4.x, a4.y, a4.z, a4.w};
      float bv[4] = {b4.x, b4.y, b4.z, b4.w};
#pragma unroll
      for (int i = 0; i < 4; i++)
#pragma unroll
        for (int j = 0; j < 4; j++) acc[i][j] += a[i] * bv[j];
    }
  }
#pragma unroll
  for (int i = 0; i < 4; i++) {
    float* yr = yb + (size_t)(row0 + ty * 4 + i) * HW + col0 + tx * 4;
    *reinterpret_cast<float4*>(yr) = make_float4(acc[i][0], acc[i][1], acc[i][2], acc[i][3]);
  }
}

// ---------------- fused sample(64x64) + MaxPool2d_G -> 32x32, 1024 threads ---------
__global__ __launch_bounds__(1024, 4) void sampmax_kernel(
    const float* __restrict__ y, const float* __restrict__ geo,
    const float* __restrict__ box, float* __restrict__ out) {
  __shared__ __align__(16) float sp[64 * 68];      // sampled plane, padded stride
  __shared__ __align__(16) float arena[64 * 100];  // padded pl (ph1) then cb (ph2-3)
  __shared__ float wv[16];
  __shared__ int wi[16];
  __shared__ int am_s;
  float* pl = arena;   // 67*68 = 4556 <= 6400
  float* cb = arena;

  int bc = blockIdx.x;
  int c = bc & (CC - 1);
  int tid = threadIdx.x;

  // Phase 0: load plane into padded layout + zero borders
  if (tid < 68) {
    pl[tid] = 0.0f; pl[65 * 68 + tid] = 0.0f; pl[66 * 68 + tid] = 0.0f;
  } else if (tid < 132) {
    int r = tid - 67;
    pl[r * 68 + 0] = 0.0f; pl[r * 68 + 65] = 0.0f; pl[r * 68 + 66] = 0.0f;
  }
  {
    const float* plane = y + (size_t)bc * 4096;
    float4 f = *reinterpret_cast<const float4*>(&plane[tid * 4]);
    int h = tid >> 4, w = (tid & 15) * 4;
    float* d = &pl[(h + 1) * 68 + w + 1];
    d[0] = f.x; d[1] = f.y; d[2] = f.z; d[3] = f.w;
  }
  __syncthreads();

  {
    const float* g = geo + c * 6;
    const float* bx = box + c * 6;
    float g0 = g[0], g1 = g[1], g2 = g[2], g3 = g[3], g4 = g[4], g5 = g[5];
    float b0 = bx[0], b1 = bx[1], b2 = bx[2], b3 = bx[3], b4 = bx[4], b5 = bx[5];
#pragma unroll
    for (int k = 0; k < 4; ++k) {
      int px = tid + k * 1024;
      int h = px >> 6, w = px & 63;
      float xs = (2.0f * w + 1.0f) / 64.0f - 1.0f;
      float ys = (2.0f * h + 1.0f) / 64.0f - 1.0f;
      float ix = ((g0 * xs + g1 * ys + g2 + 1.0f) * 64.0f - 1.0f) * 0.5f;
      float iy = ((g3 * xs + g4 * ys + g5 + 1.0f) * 64.0f - 1.0f) * 0.5f;
      float samp = sample_pad(pl, 68, 64.0f, ix, iy);
      float bix = ((b0 * xs + b1 * ys + b2 + 1.0f) * 64.0f - 1.0f) * 0.5f;
      float biy = ((b3 * xs + b4 * ys + b5 + 1.0f) * 64.0f - 1.0f) * 0.5f;
      sp[h * 68 + w] = samp * box_mask(bix, biy, 63.0f);
    }
  }
  __syncthreads();

  // Phase 2: vertical 32-row box sums, sliding window across the 4 rows per strip.
  if (tid < 256) {
    int strip = tid >> 4, w4 = (tid & 15) * 4;
    int h0 = strip * 4;
    float4 a = make_float4(0.f, 0.f, 0.f, 0.f);
    float4 keep0 = a, keep1 = a, keep2 = a;
#pragma unroll
    for (int j = 0; j < 32; ++j) {
      int r = h0 + j - 16;
      bool valid = (r >= 0) && (r < 64);
      int rc = valid ? r : 0;
      float4 f = *reinterpret_cast<const float4*>(&sp[rc * 68 + w4]);
      f.x = valid ? f.x : 0.0f; f.y = valid ? f.y : 0.0f;
      f.z = valid ? f.z : 0.0f; f.w = valid ? f.w : 0.0f;
      if (j == 0) keep0 = f;
      if (j == 1) keep1 = f;
      if (j == 2) keep2 = f;
      a.x += f.x; a.y += f.y; a.z += f.z; a.w += f.w;
    }
    *reinterpret_cast<float4*>(&cb[(h0 + 0) * 100 + 16 + w4]) = a;
#pragma unroll
    for (int j = 32; j < 35; ++j) {
      int r = h0 + j - 16;
      bool valid = (r < 64);
      int rc = valid ? r : 0;
      float4 f = *reinterpret_cast<const float4*>(&sp[rc * 68 + w4]);
      f.x = valid ? f.x : 0.0f; f.y = valid ? f.y : 0.0f;
      f.z = valid ? f.z : 0.0f; f.w = valid ? f.w : 0.0f;
      float4 kp = (j == 32) ? keep0 : ((j == 33) ? keep1 : keep2);
      a.x += f.x - kp.x; a.y += f.y - kp.y; a.z += f.z - kp.z; a.w += f.w - kp.w;
      *reinterpret_cast<float4*>(&cb[(h0 + j - 31) * 100 + 16 + w4]) = a;
    }
  } else if (tid < 768) {
    int l = tid - 256;
    int row = l >> 3, gq = l & 7;
    int base = row * 100 + ((gq < 4) ? gq * 4 : 80 + (gq - 4) * 4);
    *reinterpret_cast<float4*>(&cb[base]) = make_float4(0.f, 0.f, 0.f, 0.f);
  }
  __syncthreads();

  // Phase 3: horizontal 32-col box sums, sliding window across 4 cols per thread.
  float best = -3.402823466e+38f;
  int bidx = 0x7fffffff;
  {
    int h = tid >> 4, w4 = (tid & 15) * 4;
    float s0 = 0.f, k0 = 0.f, k1 = 0.f, k2 = 0.f;
#pragma unroll
    for (int q = 0; q < 8; ++q) {
      float4 f = *reinterpret_cast<const float4*>(&cb[h * 100 + w4 + 4 * q]);
      if (q == 0) { k0 = f.x; k1 = f.y; k2 = f.z; }
      s0 += f.x; s0 += f.y; s0 += f.z; s0 += f.w;
    }
    float4 ft = *reinterpret_cast<const float4*>(&cb[h * 100 + w4 + 32]);
    float s1 = s0 - k0 + ft.x;
    float s2 = s1 - k1 + ft.y;
    float s3 = s2 - k2 + ft.z;
    float sv[4] = {s0, s1, s2, s3};
#pragma unroll
    for (int d = 0; d < 4; ++d) {
      int i = (h << 6) + w4 + d;
      if (sv[d] > best) { best = sv[d]; bidx = i; }
    }
  }
#pragma unroll
  for (int off = 32; off > 0; off >>= 1) {
    float v2 = __shfl_down(best, off);
    int i2 = __shfl_down(bidx, off);
    if (v2 > best || (v2 == best && i2 < bidx)) { best = v2; bidx = i2; }
  }
  if ((tid & 63) == 0) { wv[tid >> 6] = best; wi[tid >> 6] = bidx; }
  __syncthreads();
  if (tid == 0) {
    float bv = wv[0]; int bi = wi[0];
#pragma unroll
    for (int k = 1; k < 16; ++k)
      if (wv[k] > bv || (wv[k] == bv && wi[k] < bi)) { bv = wv[k]; bi = wi[k]; }
    am_s = bi;
  }
  __syncthreads();

  int am = am_s;
  int r = am >> 6, cx = am & 63;
  float* o = out + (size_t)bc * 1024;
  {
    int oi = tid >> 5, oj = tid & 31;
    int rr = r + oi - 16, cj = cx + oj - 16;
    bool v = (rr >= 0) && (rr < 64) && (cj >= 0) && (cj < 64);
    int rrc = v ? rr : 0, cjc = v ? cj : 0;
    o[tid] = v ? sp[rrc * 68 + cjc] : 0.0f;
  }
}

// ---------------- fused 32x32 layer: GEMM (2 ch/block, grid 512) + sample + pool ----
// POOL path folds the dense head in via per-block atomicAdd (bias pre-written by inlay).
template <bool POOL>
__global__ __launch_bounds__(256) void fused32_kernel(
    const float* __restrict__ lin, const float* __restrict__ x,
    const float* __restrict__ geo, const float* __restrict__ box,
    float* __restrict__ out, const float* __restrict__ dw,
    float* __restrict__ head) {
  const int H = 32, W = 32, HW = 1024;
  __shared__ float pls[2][35 * 36];   // padded planes, interior rows/cols 1..32
  __shared__ float wred[8];
  __shared__ float wsum[2];
  int b = blockIdx.x & 7;                 // XCD swizzle: batch per XCD
  int c0 = (blockIdx.x >> 3) * 2;
  int tid = threadIdx.x;
  const float* xb = x + (size_t)b * 128 * HW;
  const float* l0 = lin + (c0 + 0) * 128;
  const float* l1 = lin + (c0 + 1) * 128;
  int px4 = tid * 4;

  // zero borders of both padded planes: rows 0,33,34 and cols 0,33,34,35
  if (tid < 36) {
#pragma unroll
    for (int cch = 0; cch < 2; ++cch) {
      pls[cch][tid] = 0.0f;
      pls[cch][33 * 36 + tid] = 0.0f;
      pls[cch][34 * 36 + tid] = 0.0f;
    }
  } else if (tid < 68) {
    int r = tid - 35;  // 1..32
#pragma unroll
    for (int cch = 0; cch < 2; ++cch) {
      pls[cch][r * 36 + 0] = 0.0f;
      pls[cch][r * 36 + 33] = 0.0f;
      pls[cch][r * 36 + 34] = 0.0f;
      pls[cch][r * 36 + 35] = 0.0f;
    }
  }

  float4 acc0 = make_float4(0.f, 0.f, 0.f, 0.f);
  float4 acc1 = acc0;
#pragma unroll 8
  for (int k = 0; k < 128; ++k) {
    float4 xv = *reinterpret_cast<const float4*>(&xb[(size_t)k * HW + px4]);
    float s0 = l0[k], s1 = l1[k];          // block-uniform -> s_load
    acc0.x += s0 * xv.x; acc0.y += s0 * xv.y; acc0.z += s0 * xv.z; acc0.w += s0 * xv.w;
    acc1.x += s1 * xv.x; acc1.y += s1 * xv.y; acc1.z += s1 * xv.z; acc1.w += s1 * xv.w;
  }
  {
    int h = px4 >> 5, w = px4 & 31;
    float* d0 = &pls[0][(h + 1) * 36 + w + 1];
    d0[0] = acc0.x; d0[1] = acc0.y; d0[2] = acc0.z; d0[3] = acc0.w;
    float* d1 = &pls[1][(h + 1) * 36 + w + 1];
    d1[0] = acc1.x; d1[1] = acc1.y; d1[2] = acc1.z; d1[3] = acc1.w;
  }
  __syncthreads();

  float psum[2] = {0.f, 0.f};
#pragma unroll
  for (int c = 0; c < 2; ++c) {
    const float* g = geo + (c0 + c) * 6;
    const float* bxp = box + (c0 + c) * 6;
    float g0 = g[0], g1 = g[1], g2 = g[2], g3 = g[3], g4 = g[4], g5 = g[5];
    float b0 = bxp[0], b1 = bxp[1], b2 = bxp[2], b3 = bxp[3], b4 = bxp[4], b5 = bxp[5];
    float* o = out + ((size_t)b * CC + c0 + c) * HW;
    const float* pl = pls[c];
#pragma unroll
    for (int k = 0; k < 4; ++k) {
      int px = tid + k * 256;
      int h = px >> 5, w = px & 31;
      float xs = (2.0f * w + 1.0f) / W - 1.0f;
      float ys = (2.0f * h + 1.0f) / H - 1.0f;
      float ix = ((g0 * xs + g1 * ys + g2 + 1.0f) * W - 1.0f) * 0.5f;
      float iy = ((g3 * xs + g4 * ys + g5 + 1.0f) * H - 1.0f) * 0.5f;
      float samp = sample_pad(pl, 36, 32.0f, ix, iy);
      float bix = ((b0 * xs + b1 * ys + b2 + 1.0f) * W - 1.0f) * 0.5f;
      float biy = ((b3 * xs + b4 * ys + b5 + 1.0f) * H - 1.0f) * 0.5f;
      float res = samp * box_mask(bix, biy, 31.0f);
      o[px] = res;
      if (POOL) psum[c] += res;
    }
  }
  if (POOL) {
    int lane = tid & 63, wid = tid >> 6;  // 4 waves
#pragma unroll
    for (int c = 0; c < 2; ++c) {
      float r = psum[c];
#pragma unroll
      for (int off = 32; off > 0; off >>= 1) r += __shfl_down(r, off);
      if (lane == 0) wred[c * 4 + wid] = r;
    }
    __syncthreads();
    if (tid < 2) {
      float t = wred[tid * 4] + wred[tid * 4 + 1] + wred[tid * 4 + 2] + wred[tid * 4 + 3];
      wsum[tid] = t * (1.0f / 1024.0f);
    }
    __syncthreads();
    if (tid < 10) {
      float s = wsum[0] * dw[tid * 128 + c0] + wsum[1] * dw[tid * 128 + c0 + 1];
      atomicAdd(&head[b * 10 + tid], s);
    }
  }
}

extern "C" void kernel_launch(void* const* d_in, const int* in_sizes, int n_in,
                              void* d_out, int out_size, void* d_ws, size_t ws_size,
                              hipStream_t stream) {
  const float* x     = (const float*)d_in[0];   // [8,3,64,64]
  const float* geo0  = (const float*)d_in[1];   // [128,2,3]
  const float* lin0  = (const float*)d_in[2];   // [128,3]
  const float* box0  = (const float*)d_in[3];   // [128,2,3]
  const float* geos  = (const float*)d_in[4];   // [3,128,2,3]
  const float* lins  = (const float*)d_in[5];   // [3,128,128]
  const float* boxes = (const float*)d_in[6];   // [3,128,2,3]
  const float* dw    = (const float*)d_in[7];   // [10,128]
  const float* db    = (const float*)d_in[8];   // [10]

  float* out  = (float*)d_out;      // [8,10] then feat [8,128,32,32]
  float* feat = out + 80;
  float* ws   = (float*)d_ws;
  float* ws0  = ws;                 // 16 MB
  float* ws1  = ws + 4194304;       // 16 MB

  // inLay: fused combine(Ci=3) + sample -> ws1; also writes head bias
  inlay_sample_kernel<<<dim3(BB * CC), 256, 0, stream>>>(x, lin0, geo0, box0, db, ws1, out);
  // layer 0: combine (64x64 tiles) -> fused sample+maxpool -> 32x32
  gemm64_kernel<<<dim3(64, 2, BB), 256, 0, stream>>>(lins, ws1, ws0, 4096);
  sampmax_kernel<<<dim3(BB * CC), 1024, 0, stream>>>(ws0, geos, boxes, ws1);
  // layer 2: fused GEMM + sample (2 ch/block, grid 512)
  fused32_kernel<false><<<dim3(512), 256, 0, stream>>>(lins + 16384, ws1, geos + 768, boxes + 768, ws0, nullptr, nullptr);
  // layer 3: fused GEMM + sample + mean-pool + atomic dense head, feat straight to d_out
  fused32_kernel<true><<<dim3(512), 256, 0, stream>>>(lins + 32768, ws0, geos + 1536, boxes + 1536, feat, dw, out);
}

// Round 3
// 151.693 us; speedup vs baseline: 1.1067x; 1.0381x over previous
//
#include <hip/hip_runtime.h>

#define BB 8
#define CC 128

// Bilinear sample from a zero-border padded LDS plane.
// pl is [H+3][stride] with interior pixel (r,c) at pl[(r+1)*stride + (c+1)],
// border rows/cols are 0. Coords clamped to [-1, W]; out-of-range taps read 0.
__device__ __forceinline__ float sample_pad(const float* __restrict__ pl, int stride,
                                            float WF, float ix, float iy) {
  ix = fminf(fmaxf(ix, -1.0f), WF);
  iy = fminf(fmaxf(iy, -1.0f), WF);
  float x0f = floorf(ix), y0f = floorf(iy);
  float wx = ix - x0f, wy = iy - y0f;
  int xi = (int)x0f + 1, yi = (int)y0f + 1;
  const float* p0 = pl + yi * stride + xi;
  float v00 = p0[0], v01 = p0[1], v10 = p0[stride], v11 = p0[stride + 1];
  return (1.0f - wy) * ((1.0f - wx) * v00 + wx * v01) +
         wy * ((1.0f - wx) * v10 + wx * v11);
}

// Factorized box mask: validity of tap(i,j) = X_i * Y_j, so bilinear sum = mx*my.
__device__ __forceinline__ float box_mask(float bix, float biy, float WM1) {
  float bx0 = floorf(bix), by0 = floorf(biy);
  float bwx = bix - bx0, bwy = biy - by0;
  float mx = (((bx0 >= 0.0f) && (bx0 <= WM1)) ? (1.0f - bwx) : 0.0f) +
             (((bx0 >= -1.0f) && (bx0 <= WM1 - 1.0f)) ? bwx : 0.0f);
  float my = (((by0 >= 0.0f) && (by0 <= WM1)) ? (1.0f - bwy) : 0.0f) +
             (((by0 >= -1.0f) && (by0 <= WM1 - 1.0f)) ? bwy : 0.0f);
  return mx * my;
}

// ---------------- fused inLay: combine -> padded LDS + sample + box mask ----------
__global__ __launch_bounds__(256) void inlay_sample_kernel(
    const float* __restrict__ x, const float* __restrict__ lin,
    const float* __restrict__ geo, const float* __restrict__ box,
    const float* __restrict__ db, float* __restrict__ out,
    float* __restrict__ head) {
  const int H = 64, W = 64, HW = 4096;
  __shared__ float cp[67 * 68];
  int bc = blockIdx.x;
  int c = bc & (CC - 1);
  int b = bc >> 7;
  int tid = threadIdx.x;
  if (bc == 0 && tid < 80) head[tid] = db[tid % 10];  // bias init for atomic dense
  const float* xb = x + (size_t)b * 3 * HW;

  float w0 = lin[c * 3 + 0], w1 = lin[c * 3 + 1], w2 = lin[c * 3 + 2];

  if (tid < 68) {
    cp[tid] = 0.0f; cp[65 * 68 + tid] = 0.0f; cp[66 * 68 + tid] = 0.0f;
  } else if (tid < 132) {
    int r = tid - 67;
    cp[r * 68 + 0] = 0.0f; cp[r * 68 + 65] = 0.0f; cp[r * 68 + 66] = 0.0f;
  }

#pragma unroll
  for (int k = 0; k < 4; ++k) {
    int i4 = tid + k * 256;
    int base = i4 * 4;
    float4 f0 = *reinterpret_cast<const float4*>(&xb[base]);
    float4 f1 = *reinterpret_cast<const float4*>(&xb[HW + base]);
    float4 f2 = *reinterpret_cast<const float4*>(&xb[2 * HW + base]);
    int h = i4 >> 4, w = (i4 & 15) * 4;
    float* d = &cp[(h + 1) * 68 + w + 1];
    d[0] = w0 * f0.x + w1 * f1.x + w2 * f2.x;
    d[1] = w0 * f0.y + w1 * f1.y + w2 * f2.y;
    d[2] = w0 * f0.z + w1 * f1.z + w2 * f2.z;
    d[3] = w0 * f0.w + w1 * f1.w + w2 * f2.w;
  }
  __syncthreads();

  const float* g = geo + c * 6;
  const float* bx = box + c * 6;
  float g0 = g[0], g1 = g[1], g2 = g[2], g3 = g[3], g4 = g[4], g5 = g[5];
  float b0 = bx[0], b1 = bx[1], b2 = bx[2], b3 = bx[3], b4 = bx[4], b5 = bx[5];
  float* o = out + ((size_t)b * CC + c) * HW;

#pragma unroll
  for (int k = 0; k < 16; ++k) {
    int px = tid + k * 256;
    int h = px >> 6, w = px & 63;
    float xs = (2.0f * w + 1.0f) / W - 1.0f;
    float ys = (2.0f * h + 1.0f) / H - 1.0f;
    float ix = ((g0 * xs + g1 * ys + g2 + 1.0f) * W - 1.0f) * 0.5f;
    float iy = ((g3 * xs + g4 * ys + g5 + 1.0f) * H - 1.0f) * 0.5f;
    float samp = sample_pad(cp, 68, 64.0f, ix, iy);
    float bix = ((b0 * xs + b1 * ys + b2 + 1.0f) * W - 1.0f) * 0.5f;
    float biy = ((b3 * xs + b4 * ys + b5 + 1.0f) * H - 1.0f) * 0.5f;
    o[px] = samp * box_mask(bix, biy, 63.0f);
  }
}

// ---------------- layer-0 GEMM: 64x64 tile, 4x4/thread, register prefetch ----------
__global__ __launch_bounds__(256) void gemm64_kernel(
    const float* __restrict__ lin, const float* __restrict__ x,
    float* __restrict__ y, int HW) {
  const int Ci = 128;
  __shared__ __align__(16) float As[16][68];
  __shared__ __align__(16) float Bs[16][64];
  int b = blockIdx.z;
  const float* xb = x + (size_t)b * Ci * HW;
  float* yb = y + (size_t)b * CC * HW;
  int tid = threadIdx.x;
  int tx = tid & 15, ty = tid >> 4;
  int row0 = blockIdx.y * 64;
  int col0 = blockIdx.x * 64;
  int m = tid >> 2, kq = (tid & 3) * 4;
  int kk = tid >> 4, n4 = (tid & 15) * 4;
  float acc[4][4] = {};
  float4 ra = *reinterpret_cast<const float4*>(&lin[(row0 + m) * Ci + kq]);
  float4 rb = *reinterpret_cast<const float4*>(&xb[(size_t)kk * HW + col0 + n4]);
  for (int k0 = 0; k0 < 128; k0 += 16) {
    __syncthreads();
    As[kq + 0][m] = ra.x; As[kq + 1][m] = ra.y; As[kq + 2][m] = ra.z; As[kq + 3][m] = ra.w;
    *reinterpret_cast<float4*>(&Bs[kk][n4]) = rb;
    __syncthreads();
    if (k0 + 16 < 128) {
      ra = *reinterpret_cast<const float4*>(&lin[(row0 + m) * Ci + k0 + 16 + kq]);
      rb = *reinterpret_cast<const float4*>(&xb[(size_t)(k0 + 16 + kk) * HW + col0 + n4]);
    }
#pragma unroll
    for (int kki = 0; kki < 16; ++kki) {
      float4 a4 = *reinterpret_cast<const float4*>(&As[kki][ty * 4]);
      float4 b4 = *reinterpret_cast<const float4*>(&Bs[kki][tx * 4]);
      float a[4] = {a4.x, a4.y, a4.z, a4.w};
      float bv[4] = {b4.x, b4.y, b4.z, b4.w};
#pragma unroll
      for (int i = 0; i < 4; i++)
#pragma unroll
        for (int j = 0; j < 4; j++) acc[i][j] += a[i] * bv[j];
    }
  }
#pragma unroll
  for (int i = 0; i < 4; i++) {
    float* yr = yb + (size_t)(row0 + ty * 4 + i) * HW + col0 + tx * 4;
    *reinterpret_cast<float4*>(yr) = make_float4(acc[i][0], acc[i][1], acc[i][2], acc[i][3]);
  }
}

// ---------------- fused sample(64x64) + MaxPool2d_G -> 32x32, 256 threads ---------
// 256-thr blocks: all lanes active in every phase; 35.7KB LDS -> 4 blocks/CU.
__global__ __launch_bounds__(256) void sampmax_kernel(
    const float* __restrict__ y, const float* __restrict__ geo,
    const float* __restrict__ box, float* __restrict__ out) {
  __shared__ __align__(16) float sp[64 * 68];     // sampled plane (stride 68, 16B-mult)
  __shared__ __align__(16) float arena[67 * 68];  // pl padded (ph0-1) then cb 64x68 (ph2-3)
  __shared__ float wv[4];
  __shared__ int wi[4];
  __shared__ int am_s;
  float* pl = arena;
  float* cb = arena;

  int bc = blockIdx.x;
  int c = bc & (CC - 1);
  int tid = threadIdx.x;

  // Phase 0: zero borders + load plane into padded layout
  if (tid < 68) {
    pl[tid] = 0.0f; pl[65 * 68 + tid] = 0.0f; pl[66 * 68 + tid] = 0.0f;
  } else if (tid < 132) {
    int r = tid - 67;
    pl[r * 68 + 0] = 0.0f; pl[r * 68 + 65] = 0.0f; pl[r * 68 + 66] = 0.0f;
  }
  {
    const float* plane = y + (size_t)bc * 4096;
#pragma unroll
    for (int k = 0; k < 4; ++k) {
      int i4 = tid + k * 256;
      float4 f = *reinterpret_cast<const float4*>(&plane[i4 * 4]);
      int h = i4 >> 4, w = (i4 & 15) * 4;
      float* d = &pl[(h + 1) * 68 + w + 1];
      d[0] = f.x; d[1] = f.y; d[2] = f.z; d[3] = f.w;
    }
  }
  __syncthreads();

  // Phase 1: sample 16 px/thread into sp
  {
    const float* g = geo + c * 6;
    const float* bx = box + c * 6;
    float g0 = g[0], g1 = g[1], g2 = g[2], g3 = g[3], g4 = g[4], g5 = g[5];
    float b0 = bx[0], b1 = bx[1], b2 = bx[2], b3 = bx[3], b4 = bx[4], b5 = bx[5];
#pragma unroll
    for (int k = 0; k < 16; ++k) {
      int px = tid + k * 256;
      int h = px >> 6, w = px & 63;
      float xs = (2.0f * w + 1.0f) / 64.0f - 1.0f;
      float ys = (2.0f * h + 1.0f) / 64.0f - 1.0f;
      float ix = ((g0 * xs + g1 * ys + g2 + 1.0f) * 64.0f - 1.0f) * 0.5f;
      float iy = ((g3 * xs + g4 * ys + g5 + 1.0f) * 64.0f - 1.0f) * 0.5f;
      float samp = sample_pad(pl, 68, 64.0f, ix, iy);
      float bix = ((b0 * xs + b1 * ys + b2 + 1.0f) * 64.0f - 1.0f) * 0.5f;
      float biy = ((b3 * xs + b4 * ys + b5 + 1.0f) * 64.0f - 1.0f) * 0.5f;
      sp[h * 68 + w] = samp * box_mask(bix, biy, 63.0f);
    }
  }
  __syncthreads();

  // Phase 2: vertical 32-row box sums (sliding window), all 256 threads.
  // cb[r*68 + u] = sum of sp rows r-16..r+15 at col u (zeros outside).
  {
    int strip = tid >> 4, w4 = (tid & 15) * 4;
    int h0 = strip * 4;
    float4 a = make_float4(0.f, 0.f, 0.f, 0.f);
    float4 keep0 = a, keep1 = a, keep2 = a;
#pragma unroll
    for (int j = 0; j < 32; ++j) {
      int r = h0 + j - 16;
      bool valid = (r >= 0) && (r < 64);
      int rc = valid ? r : 0;
      float4 f = *reinterpret_cast<const float4*>(&sp[rc * 68 + w4]);
      f.x = valid ? f.x : 0.0f; f.y = valid ? f.y : 0.0f;
      f.z = valid ? f.z : 0.0f; f.w = valid ? f.w : 0.0f;
      if (j == 0) keep0 = f;
      if (j == 1) keep1 = f;
      if (j == 2) keep2 = f;
      a.x += f.x; a.y += f.y; a.z += f.z; a.w += f.w;
    }
    *reinterpret_cast<float4*>(&cb[(h0 + 0) * 68 + w4]) = a;
#pragma unroll
    for (int j = 32; j < 35; ++j) {
      int r = h0 + j - 16;
      bool valid = (r < 64);
      int rc = valid ? r : 0;
      float4 f = *reinterpret_cast<const float4*>(&sp[rc * 68 + w4]);
      f.x = valid ? f.x : 0.0f; f.y = valid ? f.y : 0.0f;
      f.z = valid ? f.z : 0.0f; f.w = valid ? f.w : 0.0f;
      float4 kp = (j == 32) ? keep0 : ((j == 33) ? keep1 : keep2);
      a.x += f.x - kp.x; a.y += f.y - kp.y; a.z += f.z - kp.z; a.w += f.w - kp.w;
      *reinterpret_cast<float4*>(&cb[(h0 + j - 31) * 68 + w4]) = a;
    }
  }
  __syncthreads();

  // Phase 3: horizontal 32-col box sums (sliding window), masked group reads.
  float best = -3.402823466e+38f;
  int bidx = 0x7fffffff;
#pragma unroll
  for (int hh = 0; hh < 4; ++hh) {
    int h = (tid >> 4) + hh * 16;
    int w4 = (tid & 15) * 4;
    float s0 = 0.f, k0 = 0.f, k1 = 0.f, k2 = 0.f;
#pragma unroll
    for (int q = 0; q < 8; ++q) {
      int u0 = w4 - 16 + 4 * q;
      bool ok = (u0 >= 0) && (u0 <= 60);
      int uc = ok ? u0 : 0;
      float4 f = *reinterpret_cast<const float4*>(&cb[h * 68 + uc]);
      f.x = ok ? f.x : 0.0f; f.y = ok ? f.y : 0.0f;
      f.z = ok ? f.z : 0.0f; f.w = ok ? f.w : 0.0f;
      if (q == 0) { k0 = f.x; k1 = f.y; k2 = f.z; }
      s0 += f.x; s0 += f.y; s0 += f.z; s0 += f.w;
    }
    float ftx = 0.f, fty = 0.f, ftz = 0.f;
    {
      int u0 = w4 + 16;
      bool ok = (u0 <= 60);
      int uc = ok ? u0 : 0;
      float4 f = *reinterpret_cast<const float4*>(&cb[h * 68 + uc]);
      ftx = ok ? f.x : 0.0f; fty = ok ? f.y : 0.0f; ftz = ok ? f.z : 0.0f;
    }
    float s1 = s0 - k0 + ftx;
    float s2 = s1 - k1 + fty;
    float s3 = s2 - k2 + ftz;
    float sv[4] = {s0, s1, s2, s3};
#pragma unroll
    for (int d = 0; d < 4; ++d) {
      int i = (h << 6) + w4 + d;
      if (sv[d] > best) { best = sv[d]; bidx = i; }
    }
  }
#pragma unroll
  for (int off = 32; off > 0; off >>= 1) {
    float v2 = __shfl_down(best, off);
    int i2 = __shfl_down(bidx, off);
    if (v2 > best || (v2 == best && i2 < bidx)) { best = v2; bidx = i2; }
  }
  if ((tid & 63) == 0) { wv[tid >> 6] = best; wi[tid >> 6] = bidx; }
  __syncthreads();
  if (tid == 0) {
    float bv = wv[0]; int bi = wi[0];
#pragma unroll
    for (int k = 1; k < 4; ++k)
      if (wv[k] > bv || (wv[k] == bv && wi[k] < bi)) { bv = wv[k]; bi = wi[k]; }
    am_s = bi;
  }
  __syncthreads();

  int am = am_s;
  int r = am >> 6, cx = am & 63;
  float* o = out + (size_t)bc * 1024;
#pragma unroll
  for (int k = 0; k < 4; ++k) {
    int idx = tid + k * 256;
    int oi = idx >> 5, oj = idx & 31;
    int rr = r + oi - 16, cj = cx + oj - 16;
    bool v = (rr >= 0) && (rr < 64) && (cj >= 0) && (cj < 64);
    int rrc = v ? rr : 0, cjc = v ? cj : 0;
    o[idx] = v ? sp[rrc * 68 + cjc] : 0.0f;
  }
}

// ---------------- tiled 32x32-layer GEMM: 32x64 tiles, 2x4/thread ----------
// Replaces fused32's naive GEMM: per-layer operand traffic 268MB -> ~16MB.
__global__ __launch_bounds__(256) void gemm32_kernel(
    const float* __restrict__ lin, const float* __restrict__ x,
    float* __restrict__ y) {
  const int Ci = 128, HW = 1024;
  __shared__ __align__(16) float As[16][36];
  __shared__ __align__(16) float Bs[16][64];
  int b = blockIdx.z;
  const float* xb = x + (size_t)b * Ci * HW;
  float* yb = y + (size_t)b * CC * HW;
  int tid = threadIdx.x;
  int tx = tid & 15, ty = tid >> 4;          // ty 0..15 -> rows ty*2, ty*2+1
  int row0 = blockIdx.y * 32;
  int col0 = blockIdx.x * 64;
  int m = tid >> 2, kq = (tid & 3) * 4;      // tid<128 loads A
  int kk = tid >> 4, n4 = (tid & 15) * 4;
  float acc[2][4] = {};
  float4 ra = make_float4(0.f, 0.f, 0.f, 0.f);
  if (tid < 128) ra = *reinterpret_cast<const float4*>(&lin[(row0 + m) * Ci + kq]);
  float4 rb = *reinterpret_cast<const float4*>(&xb[(size_t)kk * HW + col0 + n4]);
  for (int k0 = 0; k0 < 128; k0 += 16) {
    __syncthreads();
    if (tid < 128) { As[kq + 0][m] = ra.x; As[kq + 1][m] = ra.y; As[kq + 2][m] = ra.z; As[kq + 3][m] = ra.w; }
    *reinterpret_cast<float4*>(&Bs[kk][n4]) = rb;
    __syncthreads();
    if (k0 + 16 < 128) {
      if (tid < 128) ra = *reinterpret_cast<const float4*>(&lin[(row0 + m) * Ci + k0 + 16 + kq]);
      rb = *reinterpret_cast<const float4*>(&xb[(size_t)(k0 + 16 + kk) * HW + col0 + n4]);
    }
#pragma unroll
    for (int kki = 0; kki < 16; ++kki) {
      float a0 = As[kki][ty * 2], a1 = As[kki][ty * 2 + 1];
      float4 b4 = *reinterpret_cast<const float4*>(&Bs[kki][tx * 4]);
      acc[0][0] += a0 * b4.x; acc[0][1] += a0 * b4.y; acc[0][2] += a0 * b4.z; acc[0][3] += a0 * b4.w;
      acc[1][0] += a1 * b4.x; acc[1][1] += a1 * b4.y; acc[1][2] += a1 * b4.z; acc[1][3] += a1 * b4.w;
    }
  }
#pragma unroll
  for (int i = 0; i < 2; i++) {
    float* yr = yb + (size_t)(row0 + ty * 2 + i) * HW + col0 + tx * 4;
    *reinterpret_cast<float4*>(yr) = make_float4(acc[i][0], acc[i][1], acc[i][2], acc[i][3]);
  }
}

// ---------------- 32x32 sample (+optional mean-pool + dense-head atomics) --------
template <bool POOL>
__global__ __launch_bounds__(256) void sample32_kernel(
    const float* __restrict__ y, const float* __restrict__ geo,
    const float* __restrict__ box, float* __restrict__ out,
    const float* __restrict__ dw, float* __restrict__ head) {
  const int W = 32, HW = 1024;
  __shared__ float pl[35 * 36];
  __shared__ float wred[4];
  int bc = blockIdx.x;
  int c = bc & (CC - 1);
  int b = bc >> 7;
  int tid = threadIdx.x;

  // zero borders: rows 0,33,34 full; cols 0,33,34,35 for rows 1..32
  if (tid < 36) {
    pl[tid] = 0.0f; pl[33 * 36 + tid] = 0.0f; pl[34 * 36 + tid] = 0.0f;
  } else if (tid < 68) {
    int r = tid - 35;
    pl[r * 36 + 0] = 0.0f; pl[r * 36 + 33] = 0.0f; pl[r * 36 + 34] = 0.0f; pl[r * 36 + 35] = 0.0f;
  }
  {
    const float* plane = y + (size_t)bc * HW;
    float4 f = *reinterpret_cast<const float4*>(&plane[tid * 4]);
    int h = tid >> 3, w = (tid & 7) * 4;
    float* d = &pl[(h + 1) * 36 + w + 1];
    d[0] = f.x; d[1] = f.y; d[2] = f.z; d[3] = f.w;
  }
  __syncthreads();

  const float* g = geo + c * 6;
  const float* bxp = box + c * 6;
  float g0 = g[0], g1 = g[1], g2 = g[2], g3 = g[3], g4 = g[4], g5 = g[5];
  float b0 = bxp[0], b1 = bxp[1], b2 = bxp[2], b3 = bxp[3], b4 = bxp[4], b5 = bxp[5];
  float* o = out + (size_t)bc * HW;
  float psum = 0.f;
#pragma unroll
  for (int k = 0; k < 4; ++k) {
    int px = tid + k * 256;
    int h = px >> 5, w = px & 31;
    float xs = (2.0f * w + 1.0f) / W - 1.0f;
    float ys = (2.0f * h + 1.0f) / W - 1.0f;
    float ix = ((g0 * xs + g1 * ys + g2 + 1.0f) * W - 1.0f) * 0.5f;
    float iy = ((g3 * xs + g4 * ys + g5 + 1.0f) * W - 1.0f) * 0.5f;
    float samp = sample_pad(pl, 36, 32.0f, ix, iy);
    float bix = ((b0 * xs + b1 * ys + b2 + 1.0f) * W - 1.0f) * 0.5f;
    float biy = ((b3 * xs + b4 * ys + b5 + 1.0f) * W - 1.0f) * 0.5f;
    float res = samp * box_mask(bix, biy, 31.0f);
    o[px] = res;
    if (POOL) psum += res;
  }
  if (POOL) {
    int lane = tid & 63, wid = tid >> 6;  // 4 waves
    float r = psum;
#pragma unroll
    for (int off = 32; off > 0; off >>= 1) r += __shfl_down(r, off);
    if (lane == 0) wred[wid] = r;
    __syncthreads();
    if (tid < 10) {
      float t = (wred[0] + wred[1] + wred[2] + wred[3]) * (1.0f / 1024.0f);
      atomicAdd(&head[b * 10 + tid], t * dw[tid * 128 + c]);
    }
  }
}

extern "C" void kernel_launch(void* const* d_in, const int* in_sizes, int n_in,
                              void* d_out, int out_size, void* d_ws, size_t ws_size,
                              hipStream_t stream) {
  const float* x     = (const float*)d_in[0];   // [8,3,64,64]
  const float* geo0  = (const float*)d_in[1];   // [128,2,3]
  const float* lin0  = (const float*)d_in[2];   // [128,3]
  const float* box0  = (const float*)d_in[3];   // [128,2,3]
  const float* geos  = (const float*)d_in[4];   // [3,128,2,3]
  const float* lins  = (const float*)d_in[5];   // [3,128,128]
  const float* boxes = (const float*)d_in[6];   // [3,128,2,3]
  const float* dw    = (const float*)d_in[7];   // [10,128]
  const float* db    = (const float*)d_in[8];   // [10]

  float* out  = (float*)d_out;      // [8,10] then feat [8,128,32,32]
  float* feat = out + 80;
  float* ws   = (float*)d_ws;
  float* ws0  = ws;                 // 16 MB regions
  float* ws1  = ws + 4194304;
  float* ws2  = ws + 8388608;

  // inLay: fused combine(Ci=3) + sample -> ws1; also writes head bias
  inlay_sample_kernel<<<dim3(BB * CC), 256, 0, stream>>>(x, lin0, geo0, box0, db, ws1, out);
  // layer 0: combine (64x64 tiles) -> fused sample+maxpool -> 32x32
  gemm64_kernel<<<dim3(64, 2, BB), 256, 0, stream>>>(lins, ws1, ws0, 4096);
  sampmax_kernel<<<dim3(BB * CC), 256, 0, stream>>>(ws0, geos, boxes, ws1);
  // layer 2: tiled GEMM then sample
  gemm32_kernel<<<dim3(16, 4, BB), 256, 0, stream>>>(lins + 16384, ws1, ws2);
  sample32_kernel<false><<<dim3(BB * CC), 256, 0, stream>>>(ws2, geos + 768, boxes + 768, ws0, nullptr, nullptr);
  // layer 3: tiled GEMM then sample + mean-pool + dense head
  gemm32_kernel<<<dim3(16, 4, BB), 256, 0, stream>>>(lins + 32768, ws0, ws2);
  sample32_kernel<true><<<dim3(BB * CC), 256, 0, stream>>>(ws2, geos + 1536, boxes + 1536, feat, dw, out);
}